// Round 16
// baseline (4176.143 us; speedup 1.0000x reference)
//
#include <hip/hip_runtime.h>
#include <math.h>

typedef unsigned long long u64;
typedef unsigned int u32;

#define N_HID   1024
#define NBATCH  128
#define TSTEPS  500
#define DT      0.05f
#define THETA   0.1f

// Geometry identical to bit-exact R8/R15: WG = 256 thr, 8-batch x 64-col
// tile, thread tile 4b x 4c, k-split 8 (KSEG=128). 16 groups x 16 ctiles
// = 256 WGs, 1/CU cooperative. Per-output FP summation order unchanged.
// R16 = R15 + (1) hyv carried in registers, (2) sh_part stride 68 (bank-
// conflict-free epilogue), (3) two-phase poll/stage/fma (phase B's sync
// chain hides under phase A's fma). NO wreg (condemned by R12).
#define B_WG   8
#define C_WG   64
#define KSPL   8
#define KSEG   (N_HID / KSPL)      // 128
#define NGRP   (NBATCH / B_WG)     // 16
#define NCT    (N_HID / C_WG)      // 16
#define NWG    (NGRP * NCT)        // 256
#define PLD    68                  // padded sh_part row stride (17 float4)

// Sync: per-group, per-producer, PER-WAVE epoch flags (R14/R15-proven).
#define CTRL_TOT    0
#define CTRL_GRP    64                      // group g: 64 flags at +g*64
#define CTRL_WORDS  (CTRL_GRP + NGRP * 64)

__device__ __forceinline__ u32 a_ld32(const u32* p) {
    return __hip_atomic_load(p, __ATOMIC_RELAXED, __HIP_MEMORY_SCOPE_AGENT);
}
__device__ __forceinline__ void a_st32(u32* p, u32 v) {
    __hip_atomic_store(p, v, __ATOMIC_RELAXED, __HIP_MEMORY_SCOPE_AGENT);
}
__device__ __forceinline__ u64 a_ld64(const u64* p) {
    return __hip_atomic_load(p, __ATOMIC_RELAXED, __HIP_MEMORY_SCOPE_AGENT);
}
__device__ __forceinline__ void a_st64(u64* p, u64 v) {
    __hip_atomic_store(p, v, __ATOMIC_RELAXED, __HIP_MEMORY_SCOPE_AGENT);
}

// exact fma sequence (order-identical to R2..R15 kernels)
#define FMA16(hv, wv4) do { \
    acc[0][0]=fmaf((hv).x,(wv4).x,acc[0][0]); acc[0][1]=fmaf((hv).x,(wv4).y,acc[0][1]); \
    acc[0][2]=fmaf((hv).x,(wv4).z,acc[0][2]); acc[0][3]=fmaf((hv).x,(wv4).w,acc[0][3]); \
    acc[1][0]=fmaf((hv).y,(wv4).x,acc[1][0]); acc[1][1]=fmaf((hv).y,(wv4).y,acc[1][1]); \
    acc[1][2]=fmaf((hv).y,(wv4).z,acc[1][2]); acc[1][3]=fmaf((hv).y,(wv4).w,acc[1][3]); \
    acc[2][0]=fmaf((hv).z,(wv4).x,acc[2][0]); acc[2][1]=fmaf((hv).z,(wv4).y,acc[2][1]); \
    acc[2][2]=fmaf((hv).z,(wv4).z,acc[2][2]); acc[2][3]=fmaf((hv).z,(wv4).w,acc[2][3]); \
    acc[3][0]=fmaf((hv).w,(wv4).x,acc[3][0]); acc[3][1]=fmaf((hv).w,(wv4).y,acc[3][1]); \
    acc[3][2]=fmaf((hv).w,(wv4).z,acc[3][2]); acc[3][3]=fmaf((hv).w,(wv4).w,acc[3][3]); \
} while (0)

__global__ __launch_bounds__(256, 1) void persist_kernel(
    const float* __restrict__ x,
    const float* __restrict__ W,       // (1024,1024) row-major [k][c]
    const float* __restrict__ x2h,
    const float* __restrict__ bias,
    const float* __restrict__ gam,
    const float* __restrict__ eps,
    float* __restrict__ hyT0,          // (1024,128) ping
    float* __restrict__ hyT1,          // (1024,128) pong
    float* __restrict__ uout,          // (128,1024)
    u32* __restrict__ ctrl,
    float alpha, float oma)
{
    // sh_hyT: WAVE-PRIVATE (wave stages and reads only its own 256 rows)
    // -> single buffer, no barrier protection needed.
    // sh_part: cross-wave -> parity double-buffered, padded stride PLD.
    __shared__ float sh_hyT[N_HID * B_WG];            // 32 KB [k][8b]
    __shared__ float sh_part[2][KSPL * B_WG * PLD];   // 2 x 17.4 KB
    __shared__ u32 sh_cnt;

    const int tid = threadIdx.x;
    if (tid == 0) sh_cnt = 0u;

    // XCD swizzle (R5): XCD (bid&7) owns 2 ctiles -> 512 KB W slice hot in L2.
    const int bid   = blockIdx.x;
    const int xcd   = bid & 7;
    const int idx   = bid >> 3;
    const int ctile = xcd * 2 + (idx & 1);
    const int btile = idx >> 1;
    const int c0g   = ctile * C_WG;
    const int b0    = btile * B_WG;

    // GEMM thread mapping (R8)
    const int cg  = tid & 15;
    const int bg  = (tid >> 4) & 1;
    const int ks  = tid >> 5;          // 0..7
    const int bl0 = bg * 4;
    const int k0  = ks * KSEG;
    const float* Wp = W + (size_t)k0 * N_HID + c0g + cg * 4;

    // wave mapping: wave wv owns hy rows [256*wv, 256*wv+256)
    const int wv   = tid >> 6;         // 0..3
    const int lane = tid & 63;
    u32* flags = ctrl + CTRL_GRP + (btile << 6);     // 64 flags (256 B)
    // two-phase poll: phase A needs ctiles {4wv, 4wv+2} (fma kk 0..63),
    // phase B needs {4wv+1, 4wv+3} (fma kk 64..127); 8 wave-flags each.
    const int pbaseA = ((lane & 4) ? (4 * wv + 2) : (4 * wv)) * 4 + (lane & 3);
    const int pbaseB = ((lane & 4) ? (4 * wv + 3) : (4 * wv + 1)) * 4 + (lane & 3);
    u32* mypollA = flags + pbaseA;
    u32* mypollB = flags + pbaseB;
    u32* mypub   = flags + ctile * 4 + wv;           // this wave's slot

    // epilogue mapping (R15): thread owns (row c2, batches b2, b2+1)
    const int c2  = tid >> 2;          // 0..63
    const int b2  = (tid & 3) * 2;     // 0,2,4,6
    const int cgl = c0g + c2;
    const float x2h_c  = x2h[cgl];
    const float bias_c = bias[cgl];
    const float gam_c  = gam[cgl];
    const float eps_c  = eps[cgl];
    const float* xrow0 = x + (size_t)(b0 + b2)     * TSTEPS;
    const float* xrow1 = x + (size_t)(b0 + b2 + 1) * TSTEPS;

    // persistent state: hz, u, AND hy of this thread's own two outputs
    // (hyv(t) == the hyn this thread computed at step t-1 -> register)
    float hz0 = 0.f, hz1 = 0.f, u0 = 0.f, u1 = 0.f;
    float hyp0 = 0.f, hyp1 = 0.f;      // hy(0) == 0 exactly
    u32 spikes = 0;

    for (int t = 0; t < TSTEPS; ++t) {
        const float* src = (t & 1) ? hyT1 : hyT0;   // hy(t)   (t>=1)
        float*       dst = (t & 1) ? hyT0 : hyT1;   // hy(t+1)
        float* part = sh_part[t & 1];

        // x prefetch: latency hides under poll+stage+fma
        const float xa = xrow0[t];
        const float xb = xrow1[t];

        float acc[4][4];
        #pragma unroll
        for (int i = 0; i < 4; ++i)
            #pragma unroll
            for (int jj = 0; jj < 4; ++jj) acc[i][jj] = 0.f;

        u64* s64 = (u64*)sh_hyT;
        const u64* src64 = (const u64*)src;          // row = 64 u64

        if (t == 0) {
            // hy(0) == 0 exactly: zero-fill whole wave range, then both fma
            // phases over zeros (bit-exact with staged zeros)
            #pragma unroll
            for (int it = 0; it < 16; ++it)
                s64[(wv << 10) + it * 64 + lane] = 0ull;
            asm volatile("" ::: "memory");
            #pragma unroll 8
            for (int kk = 0; kk < KSEG; ++kk) {
                const float4 hv  = *(const float4*)(&sh_hyT[(k0 + kk) * B_WG + bl0]);
                const float4 wv4 = *(const float4*)(Wp + (size_t)kk * N_HID);
                FMA16(hv, wv4);
            }
        } else {
            // ---- PHASE A: ctiles {4wv, 4wv+2} -> wave-rel rows
            //      [0,64) u [128,192) -> fma kk 0..63 ----
            while (!__all(a_ld32(mypollA) >= (u32)t))
                __builtin_amdgcn_s_sleep(1);
            {
                u64 tmp[8];
                #pragma unroll
                for (int it = 0; it < 8; ++it) {
                    const int e     = it * 64 + lane;   // 0..511
                    const int k_rel = e >> 2;           // 0..127
                    const int pair  = e & 3;
                    const int kA    = k_rel + ((k_rel >> 6) << 6); // 0..63,128..191
                    tmp[it] = a_ld64(src64 + (size_t)((wv << 8) + kA) * 64
                                     + (b0 >> 1) + pair);
                }
                #pragma unroll
                for (int it = 0; it < 8; ++it) {
                    const int e     = it * 64 + lane;
                    const int k_rel = e >> 2;
                    const int pair  = e & 3;
                    const int kA    = k_rel + ((k_rel >> 6) << 6);
                    s64[(wv << 10) + kA * 4 + pair] = tmp[it];
                }
            }
            asm volatile("" ::: "memory");   // stage writes before fma reads
            #pragma unroll 8
            for (int kk = 0; kk < 64; ++kk) {
                const float4 hv  = *(const float4*)(&sh_hyT[(k0 + kk) * B_WG + bl0]);
                const float4 wv4 = *(const float4*)(Wp + (size_t)kk * N_HID);
                FMA16(hv, wv4);
            }
            asm volatile("" ::: "memory");

            // ---- PHASE B: ctiles {4wv+1, 4wv+3} -> wave-rel rows
            //      [64,128) u [192,256) -> fma kk 64..127 ----
            while (!__all(a_ld32(mypollB) >= (u32)t))
                __builtin_amdgcn_s_sleep(1);
            {
                u64 tmp[8];
                #pragma unroll
                for (int it = 0; it < 8; ++it) {
                    const int e     = it * 64 + lane;
                    const int k_rel = e >> 2;
                    const int pair  = e & 3;
                    const int kB    = k_rel + 64 + ((k_rel >> 6) << 6); // 64..127,192..255
                    tmp[it] = a_ld64(src64 + (size_t)((wv << 8) + kB) * 64
                                     + (b0 >> 1) + pair);
                }
                #pragma unroll
                for (int it = 0; it < 8; ++it) {
                    const int e     = it * 64 + lane;
                    const int k_rel = e >> 2;
                    const int pair  = e & 3;
                    const int kB    = k_rel + 64 + ((k_rel >> 6) << 6);
                    s64[(wv << 10) + kB * 4 + pair] = tmp[it];
                }
            }
            asm volatile("" ::: "memory");
            #pragma unroll 8
            for (int kk = 64; kk < KSEG; ++kk) {
                const float4 hv  = *(const float4*)(&sh_hyT[(k0 + kk) * B_WG + bl0]);
                const float4 wv4 = *(const float4*)(Wp + (size_t)kk * N_HID);
                FMA16(hv, wv4);
            }
            asm volatile("" ::: "memory");
        }

        // ---- k-segment partials -> padded LDS ----
        #pragma unroll
        for (int bi = 0; bi < 4; ++bi) {
            float4 v = make_float4(acc[bi][0], acc[bi][1], acc[bi][2], acc[bi][3]);
            *(float4*)(&part[((ks * B_WG) + bl0 + bi) * PLD + cg * 4]) = v;
        }
        __syncthreads();   // SYNC1: partials visible

        // ---- reduce (ascending, R8 order) + fused cell; hyv from regs;
        //      ONE packed coalesced u64 store ----
        float hyn0, hyn1;
        {
            float sum = part[(0 * B_WG + b2) * PLD + c2];
            #pragma unroll
            for (int s2 = 1; s2 < KSPL; ++s2)
                sum += part[(s2 * B_WG + b2) * PLD + c2];
            const float pre = tanhf(fmaf(xa, x2h_c, sum) + bias_c);
            hz0 = fmaf(DT, pre - gam_c * hyp0 - eps_c * hz0, hz0);
            hyn0 = fmaf(DT, hz0, hyp0);
            const int s = ((hyn0 - THETA) > 0.f) ? 1 : 0;
            u0 = fmaf(u0, alpha, (float)s * oma);
            spikes += (u32)s;
            hyp0 = hyn0;
        }
        {
            float sum = part[(0 * B_WG + b2 + 1) * PLD + c2];
            #pragma unroll
            for (int s2 = 1; s2 < KSPL; ++s2)
                sum += part[(s2 * B_WG + b2 + 1) * PLD + c2];
            const float pre = tanhf(fmaf(xb, x2h_c, sum) + bias_c);
            hz1 = fmaf(DT, pre - gam_c * hyp1 - eps_c * hz1, hz1);
            hyn1 = fmaf(DT, hz1, hyp1);
            const int s = ((hyn1 - THETA) > 0.f) ? 1 : 0;
            u1 = fmaf(u1, alpha, (float)s * oma);
            spikes += (u32)s;
            hyp1 = hyn1;
        }
        {
            float2 f2 = make_float2(hyn0, hyn1);
            u64 v;
            __builtin_memcpy(&v, &f2, 8);
            a_st64((u64*)(dst + (size_t)cgl * NBATCH + b0 + b2), v);
        }

        // ---- per-wave publish: drain OWN stores, then flag = t+1 ----
        asm volatile("s_waitcnt vmcnt(0)" ::: "memory");
        if (lane == 0) a_st32(mypub, (u32)(t + 1));
    }

    // ---- final: u out, spike-count reduce ----
    uout[(size_t)(b0 + b2)     * N_HID + cgl] = u0;
    uout[(size_t)(b0 + b2 + 1) * N_HID + cgl] = u1;

    u32 s = spikes;
    s += __shfl_down(s, 32);
    s += __shfl_down(s, 16);
    s += __shfl_down(s, 8);
    s += __shfl_down(s, 4);
    s += __shfl_down(s, 2);
    s += __shfl_down(s, 1);
    if ((tid & 63) == 0) atomicAdd(&sh_cnt, s);
    __syncthreads();
    if (tid == 0) atomicAdd(ctrl + CTRL_TOT, sh_cnt);
}

__global__ void init_kernel(u32* ctrl)
{
    const int i = blockIdx.x * blockDim.x + threadIdx.x;
    if (i < CTRL_WORDS) {
        __hip_atomic_store(ctrl + i, 0u, __ATOMIC_RELAXED,
                           __HIP_MEMORY_SCOPE_AGENT);
    }
}

__global__ void final_kernel(const u32* __restrict__ ctrl,
                             float* __restrict__ out_rate)
{
    if (threadIdx.x == 0 && blockIdx.x == 0) {
        const double denom = (double)NBATCH * (double)TSTEPS * (double)N_HID;
        *out_rate = (float)((double)ctrl[CTRL_TOT] / denom);
    }
}

extern "C" void kernel_launch(void* const* d_in, const int* in_sizes, int n_in,
                              void* d_out, int out_size, void* d_ws, size_t ws_size,
                              hipStream_t stream)
{
    const float* x    = (const float*)d_in[0];
    const float* h2h  = (const float*)d_in[1];
    const float* x2h  = (const float*)d_in[2];
    const float* bias = (const float*)d_in[3];
    const float* gam  = (const float*)d_in[4];
    const float* eps  = (const float*)d_in[5];

    float* out = (float*)d_out;            // u: [0,131072), rate at [131072]

    float* hyT0 = (float*)d_ws;
    float* hyT1 = hyT0 + (size_t)NBATCH * N_HID;
    u32*   ctrl = (u32*)(hyT1 + (size_t)NBATCH * N_HID);

    init_kernel<<<dim3((CTRL_WORDS + 255) / 256), dim3(256), 0, stream>>>(ctrl);

    float alpha = expf(-1.0f / 20.0f);
    float oma   = 1.0f - alpha;

    void* args[] = {
        (void*)&x, (void*)&h2h, (void*)&x2h, (void*)&bias, (void*)&gam,
        (void*)&eps, (void*)&hyT0, (void*)&hyT1, (void*)&out, (void*)&ctrl,
        (void*)&alpha, (void*)&oma
    };
    hipLaunchCooperativeKernel((const void*)persist_kernel,
                               dim3(NWG), dim3(256), args, 0, stream);

    final_kernel<<<dim3(1), dim3(64), 0, stream>>>(
        ctrl, out + (size_t)NBATCH * N_HID);
}